// Round 16
// baseline (413.282 us; speedup 1.0000x reference)
//
#include <hip/hip_runtime.h>
#include <math.h>

#define NNODES 51200
#define NEDGES 409600
#define NB 1024
#define NODES_PER 50
#define NVOCAB 100000
#define NVPAD 100096
#define SLOTS 64

typedef __attribute__((ext_vector_type(8))) short bf16x8;
typedef __attribute__((ext_vector_type(4))) float f32x4;

__device__ __forceinline__ float sigf(float x) { return 1.0f / (1.0f + __expf(-x)); }

__device__ __forceinline__ ushort f2bf(float x) {   // RTNE f32 -> bf16
    union { float f; unsigned u; } v; v.f = x;
    const unsigned r = v.u + 0x7FFF + ((v.u >> 16) & 1);
    return (ushort)(r >> 16);
}
__device__ __forceinline__ float bf2f(ushort u) {
    union { float f; unsigned u; } v; v.u = ((unsigned)u) << 16; return v.f;
}
__device__ __forceinline__ bf16x8 cvt8(const float* __restrict__ src) {
    const float4 v0 = *(const float4*)src, v1 = *(const float4*)(src + 4);
    bf16x8 p;
    p[0] = (short)f2bf(v0.x); p[1] = (short)f2bf(v0.y);
    p[2] = (short)f2bf(v0.z); p[3] = (short)f2bf(v0.w);
    p[4] = (short)f2bf(v1.x); p[5] = (short)f2bf(v1.y);
    p[6] = (short)f2bf(v1.z); p[7] = (short)f2bf(v1.w);
    return p;
}

// ---------------------------------------------------------------------------
// Mega prep kernel (independent segments):
//  [0,3200)        gather: hb[i] = bf16(emb[x[i]-1])
//  [3200,4800)     slot-CSR fill: esrc[dst*64+pos] = src
//  [4800,11056)    embswz: emb -> bf16, pre-swizzled, pad rows zeroed
//  [11056,11248)   Wc[m][n^swz] = bf16(sum_k Wih[m][k]*Wg[n][k])  (swizzled)
//  [11248,11272)   Whhb: Whh -> bf16 pre-swizzled [384][128]
//  [11272,11280)   W2b:  W2  -> bf16 pre-swizzled [128][128]
// ---------------------------------------------------------------------------
__global__ __launch_bounds__(256)
void prep_kernel(const int* __restrict__ x, const float* __restrict__ emb,
                 ushort* __restrict__ hb, const int* __restrict__ ei,
                 int* __restrict__ cnt, int* __restrict__ esrc,
                 ushort* __restrict__ embswz, const float* __restrict__ Wih,
                 const float* __restrict__ Wg, ushort* __restrict__ Wc,
                 const float* __restrict__ Whh, ushort* __restrict__ Whhb,
                 const float* __restrict__ W2, ushort* __restrict__ W2b) {
    const int bid = blockIdx.x;
    const int t = threadIdx.x;
    if (bid < 3200) {                              // gather
        const int tid = bid * 256 + t;
        const int i = tid >> 4, c8 = (tid & 15) * 8;
        const int idx = x[i] - 1;
        *(bf16x8*)(hb + (size_t)i * 128 + c8) = cvt8(emb + (size_t)idx * 128 + c8);
    } else if (bid < 4800) {                       // slot-CSR fill
        const int e = (bid - 3200) * 256 + t;
        const int dst = ei[NEDGES + e];
        const int pos = atomicAdd(&cnt[dst], 1);
        if (pos < SLOTS) esrc[(size_t)dst * SLOTS + pos] = ei[e];
    } else if (bid < 11056) {                      // embswz
        const int f = (bid - 4800) * 256 + t;      // < NVPAD*16
        const int row = f >> 4, c8 = (f & 15) * 8;
        bf16x8 pk = {0, 0, 0, 0, 0, 0, 0, 0};
        if (row < NVOCAB) pk = cvt8(emb + (size_t)row * 128 + c8);
        *(bf16x8*)&embswz[(size_t)row * 128 + (c8 ^ ((row & 7) << 3))] = pk;
    } else if (bid < 11248) {                      // Wcomb = Wih @ Wg^T, swz
        const int idx = (bid - 11056) * 256 + t;   // < 49152
        const int mrow = idx >> 7, n = idx & 127;
        const float* wr = Wih + (size_t)mrow * 128;
        const float* gr = Wg + (size_t)n * 128;
        float acc = 0.f;
        #pragma unroll 8
        for (int k = 0; k < 128; ++k)
            acc = fmaf(wr[k], gr[k], acc);
        Wc[mrow * 128 + (n ^ ((mrow & 7) << 3))] = f2bf(acc);
    } else if (bid < 11272) {                      // Whhb (swizzled bf16)
        const int f = (bid - 11248) * 256 + t;     // < 6144
        const int r = f >> 4, c8 = (f & 15) * 8;
        *(bf16x8*)&Whhb[r * 128 + (c8 ^ ((r & 7) << 3))] = cvt8(Whh + (size_t)r * 128 + c8);
    } else {                                       // W2b (swizzled bf16)
        const int f = (bid - 11272) * 256 + t;     // < 2048
        const int r = f >> 4, c8 = (f & 15) * 8;
        *(bf16x8*)&W2b[r * 128 + (c8 ^ ((r & 7) << 3))] = cvt8(W2 + (size_t)r * 128 + c8);
    }
}

// ---------------------------------------------------------------------------
// Fully fused agg + GRU: 400 blocks x 512 thr, 128 rows each.
// Phase 1 A-stage IS the gather-sum (hb read-only; output to hnew).
// ---------------------------------------------------------------------------
__global__ __launch_bounds__(512)
void gru_fused(const int* __restrict__ cnt, const int* __restrict__ esrc,
               const ushort* __restrict__ hb, const ushort* __restrict__ Wc,
               const ushort* __restrict__ Whhb, const float* __restrict__ bih,
               const float* __restrict__ bhh, ushort* __restrict__ hnew) {
    __shared__ ushort As[128 * 128];
    __shared__ ushort Bs[384 * 128];
    const int m0 = blockIdx.x * 128;
    const int t = threadIdx.x;
    const int lane = t & 63, wid = t >> 6;
    const int l15 = lane & 15, kg = (lane >> 4) * 8;

    // ---- phase 1 stage: S rows via gather-sum; Wc linear copy ----
    #pragma unroll
    for (int rr = 0; rr < 16; ++rr) {
        const int r = wid * 16 + rr;
        const int node = m0 + r;
        int cn = cnt[node]; if (cn > SLOTS) cn = SLOTS;
        const int* es = esrc + (size_t)node * SLOTS;
        float ax = 0.f, ay = 0.f;
        for (int j = 0; j < cn; ++j) {
            const int src = es[j];
            const unsigned u = *(const unsigned*)(hb + (size_t)src * 128 + lane * 2);
            ax += bf2f((ushort)(u & 0xffff));
            ay += bf2f((ushort)(u >> 16));
        }
        const unsigned o = (unsigned)f2bf(ax) | ((unsigned)f2bf(ay) << 16);
        *(unsigned*)&As[r * 128 + ((lane * 2) ^ ((r & 7) << 3))] = o;
    }
    #pragma unroll
    for (int f = t; f < 6144; f += 512)
        *(bf16x8*)&Bs[f * 8] = *(const bf16x8*)(Wc + (size_t)f * 8);
    __syncthreads();

    f32x4 gi[24] = {};
    #pragma unroll
    for (int kc = 0; kc < 4; ++kc) {
        const int cs = kc * 32 + kg;
        const int ra = wid * 16 + l15;
        const bf16x8 af = *(const bf16x8*)&As[ra * 128 + (cs ^ ((ra & 7) << 3))];
        #pragma unroll
        for (int j = 0; j < 24; ++j) {
            const int rb = j * 16 + l15;
            const bf16x8 bfr = *(const bf16x8*)&Bs[rb * 128 + (cs ^ ((rb & 7) << 3))];
            gi[j] = __builtin_amdgcn_mfma_f32_16x16x32_bf16(af, bfr, gi[j], 0, 0, 0);
        }
    }
    __syncthreads();

    // ---- phase 2: gh = h @ Whh^T (As = bf16 h, kept for epilogue) ----
    #pragma unroll
    for (int f = t; f < 2048; f += 512) {
        const int r = f >> 4, c8 = (f & 15) * 8;
        const bf16x8 pk = *(const bf16x8*)(hb + (size_t)(m0 + r) * 128 + c8);
        *(bf16x8*)&As[r * 128 + (c8 ^ ((r & 7) << 3))] = pk;
    }
    #pragma unroll
    for (int f = t; f < 6144; f += 512)
        *(bf16x8*)&Bs[f * 8] = *(const bf16x8*)(Whhb + (size_t)f * 8);
    __syncthreads();

    f32x4 gh[24] = {};
    #pragma unroll
    for (int kc = 0; kc < 4; ++kc) {
        const int cs = kc * 32 + kg;
        const int ra = wid * 16 + l15;
        const bf16x8 af = *(const bf16x8*)&As[ra * 128 + (cs ^ ((ra & 7) << 3))];
        #pragma unroll
        for (int j = 0; j < 24; ++j) {
            const int rb = j * 16 + l15;
            const bf16x8 bfr = *(const bf16x8*)&Bs[rb * 128 + (cs ^ ((rb & 7) << 3))];
            gh[j] = __builtin_amdgcn_mfma_f32_16x16x32_bf16(af, bfr, gh[j], 0, 0, 0);
        }
    }

    // ---- epilogue: gates + ReLU; hv from As; result back into As ----
    const int lr0 = wid * 16 + (lane >> 4) * 4;
    #pragma unroll
    for (int j = 0; j < 8; ++j) {
        const int col = j * 16 + l15;
        const float bir = bih[col], biz = bih[128 + col], bin = bih[256 + col];
        const float bhr = bhh[col], bhz = bhh[128 + col], bhn = bhh[256 + col];
        #pragma unroll
        for (int q = 0; q < 4; ++q) {
            const int lr = lr0 + q;
            const int adr = lr * 128 + (col ^ ((lr & 7) << 3));
            const float hv = bf2f(As[adr]);
            const float r_ = sigf(gi[j][q] + bir + gh[j][q] + bhr);
            const float z  = sigf(gi[j + 8][q] + biz + gh[j + 8][q] + bhz);
            const float ng = tanhf(gi[j + 16][q] + bin + r_ * (gh[j + 16][q] + bhn));
            As[adr] = f2bf(fmaxf((1.f - z) * ng + z * hv, 0.f));
        }
    }
    __syncthreads();
    #pragma unroll
    for (int f = t; f < 2048; f += 512) {
        const int r = f >> 4, c8 = (f & 15) * 8;
        *(bf16x8*)(hnew + (size_t)(m0 + r) * 128 + c8) =
            *(const bf16x8*)&As[r * 128 + (c8 ^ ((r & 7) << 3))];
    }
}

// ---------------------------------------------------------------------------
// Fused t2-GEMM + attention + sh: 512 blocks x 256 thr, 2 sessions each.
// ---------------------------------------------------------------------------
__global__ __launch_bounds__(256)
void attn_sh(const ushort* __restrict__ hb, const float* __restrict__ W1,
             const float* __restrict__ b1, const ushort* __restrict__ W2b,
             const float* __restrict__ qw, const float* __restrict__ qbp,
             const float* __restrict__ b2, const float* __restrict__ W3,
             const float* __restrict__ b3, ushort* __restrict__ shb) {
    __shared__ ushort As[128 * 128];     // h tile bf16 (swizzled)
    __shared__ ushort Bs[128 * 128];     // W2 bf16, then t2T bf16 [d][row]
    __shared__ float t1s[2][128];
    __shared__ float qws[128];
    __shared__ float apar[2][2][64];
    __shared__ float alph[2][64];
    __shared__ float sgs[2][128];
    const int m0 = blockIdx.x * 100;
    const int t = threadIdx.x;
    const int lane = t & 63, wid = t >> 6;
    const int wr = wid >> 1, wc = wid & 1;
    const int l15 = lane & 15, kg = (lane >> 4) * 8;
    const int cr0 = (lane >> 4) * 4;

    #pragma unroll
    for (int f = t; f < 2048; f += 256) {
        const int r = f >> 4, c8 = (f & 15) * 8;
        int gr = m0 + r; if (gr > NNODES - 1) gr = NNODES - 1;   // clamp tail
        *(bf16x8*)&As[r * 128 + (c8 ^ ((r & 7) << 3))] =
            *(const bf16x8*)(hb + (size_t)gr * 128 + c8);
        *(bf16x8*)&Bs[f * 8] = *(const bf16x8*)(W2b + (size_t)f * 8);
    }
    if (t < 128) qws[t] = qw[t];
    __syncthreads();

    // t2 = h @ W2^T
    f32x4 acc[4][4] = {};
    #pragma unroll
    for (int kc = 0; kc < 4; ++kc) {
        const int cs = kc * 32 + kg;
        bf16x8 af[4], bfr[4];
        #pragma unroll
        for (int i = 0; i < 4; ++i) {
            const int ra = wr * 64 + i * 16 + l15;
            af[i] = *(const bf16x8*)&As[ra * 128 + (cs ^ ((ra & 7) << 3))];
            const int rb = wc * 64 + i * 16 + l15;
            bfr[i] = *(const bf16x8*)&Bs[rb * 128 + (cs ^ ((rb & 7) << 3))];
        }
        #pragma unroll
        for (int i = 0; i < 4; ++i)
            #pragma unroll
            for (int j = 0; j < 4; ++j)
                acc[i][j] = __builtin_amdgcn_mfma_f32_16x16x32_bf16(af[i], bfr[j], acc[i][j], 0, 0, 0);
    }
    __syncthreads();                               // MFMA reads of Bs done

    // t2T (bf16, swizzled) overlays Bs: addr = d*128 + (row ^ ((d&7)<<3))
    #pragma unroll
    for (int j = 0; j < 4; ++j) {
        const int col = wc * 64 + j * 16 + l15;
        const int csw = (col & 7) << 3;
        #pragma unroll
        for (int i = 0; i < 4; ++i) {
            const int row = wr * 64 + i * 16 + cr0;
            #pragma unroll
            for (int q = 0; q < 4; ++q)
                Bs[col * 128 + ((row + q) ^ csw)] = f2bf(acc[i][j][q]);
        }
    }

    // t1[d] = W1[d]·vn + b1[d] + b2[d]
    const int sess = wid >> 1, half = wid & 1;
    const int d = half * 64 + lane;
    const int vrow = sess * 50 + 49;
    const int vsw = (vrow & 7) << 3;
    float t1v = b1[d] + b2[d];
    const float* w1r = W1 + (size_t)d * 128;
    #pragma unroll 8
    for (int k = 0; k < 128; k += 4) {
        const float4 w = *(const float4*)(w1r + k);
        t1v += w.x * bf2f(As[vrow * 128 + ((k + 0) ^ vsw)])
             + w.y * bf2f(As[vrow * 128 + ((k + 1) ^ vsw)])
             + w.z * bf2f(As[vrow * 128 + ((k + 2) ^ vsw)])
             + w.w * bf2f(As[vrow * 128 + ((k + 3) ^ vsw)]);
    }
    t1s[sess][d] = t1v;
    __syncthreads();

    // alphas: lane = node (l<50), sum over this half's 64 dims
    float p = 0.f;
    if (lane < 50) {
        const int row = sess * 50 + lane;
        const int d0 = half * 64;
        #pragma unroll 8
        for (int dd = d0; dd < d0 + 64; ++dd)
            p += qws[dd] * sigf(t1s[sess][dd] + bf2f(Bs[dd * 128 + (row ^ ((dd & 7) << 3))]));
    }
    apar[sess][half][lane] = p;
    __syncthreads();
    if (half == 0 && lane < 50)
        alph[sess][lane] = apar[sess][0][lane] + apar[sess][1][lane] + qbp[0];
    __syncthreads();

    // sg[d] = sum_i alpha_i * h[i][d]  (kept in LDS)
    float sacc = 0.f;
    #pragma unroll 10
    for (int i = 0; i < 50; ++i) {
        const int row = sess * 50 + i;
        sacc += alph[sess][i] * bf2f(As[row * 128 + (d ^ ((row & 7) << 3))]);
    }
    sgs[sess][d] = sacc;
    __syncthreads();

    // sh[d] = W3[d] · [vn; sg] + b3[d]  -> shb bf16 pre-swizzled
    float shacc = b3[d];
    const float* w3r = W3 + (size_t)d * 256;
    #pragma unroll 8
    for (int k = 0; k < 128; k += 4) {
        const float4 w = *(const float4*)(w3r + k);
        shacc += w.x * bf2f(As[vrow * 128 + ((k + 0) ^ vsw)])
               + w.y * bf2f(As[vrow * 128 + ((k + 1) ^ vsw)])
               + w.z * bf2f(As[vrow * 128 + ((k + 2) ^ vsw)])
               + w.w * bf2f(As[vrow * 128 + ((k + 3) ^ vsw)]);
    }
    #pragma unroll 8
    for (int k = 0; k < 128; k += 4) {
        const float4 w = *(const float4*)(w3r + 128 + k);
        shacc += w.x * sgs[sess][k] + w.y * sgs[sess][k + 1]
               + w.z * sgs[sess][k + 2] + w.w * sgs[sess][k + 3];
    }
    const int orow = blockIdx.x * 2 + sess;
    shb[(size_t)orow * 128 + (d ^ ((orow & 7) << 3))] = f2bf(shacc);
}

// ---------------------------------------------------------------------------
// Vocab GEMM: out = sh @ emb^T. 256 thr (4 waves 2x2), LDS 64 KB -> 2
// blocks/CU. A staged once (linear from shb); 2 n-tiles/block.
// Grid 3136 = 8 xcd x 8 mt x 49 g (all pairs covered; round-15 bug was a
// non-factorable 3128 grid that dropped (mt=7,g=48)). grp=391 exits early.
// ---------------------------------------------------------------------------
__global__ __launch_bounds__(256)
void gemm_vocab(float* __restrict__ C, const ushort* __restrict__ Ab,
                const ushort* __restrict__ Bswz) {
    __shared__ ushort As[128 * 128];
    __shared__ ushort Bs[128 * 128];
    float* Cs = (float*)Bs;                        // [64][128] f32 overlay
    const int id = blockIdx.x;
    const int xcd = id & 7, loc = id >> 3;         // loc 0..391
    const int mt = loc & 7, g = loc >> 3;          // mt 0..7, g 0..48
    const int grp = xcd * 49 + g;                  // 0..391
    if (grp * 256 >= NVOCAB) return;               // block-uniform early out
    const int m0 = mt * 128;
    const int t = threadIdx.x;
    const int lane = t & 63, wid = t >> 6;
    const int wr = wid >> 1, wc = wid & 1;
    const int l15 = lane & 15, kg = (lane >> 4) * 8;
    const int cr0 = (lane >> 4) * 4;

    // stage A once (linear; shb pre-swizzled)
    #pragma unroll
    for (int f = t; f < 2048; f += 256)
        *(bf16x8*)&As[f * 8] = *(const bf16x8*)(Ab + (size_t)m0 * 128 + f * 8);

    for (int it = 0; it < 2; ++it) {
        const int n0 = (grp * 2 + it) * 128;
        if (n0 >= NVOCAB) break;                   // block-uniform
        __syncthreads();                           // prev repack reads done
        const ushort* srcb = Bswz + (size_t)n0 * 128;
        #pragma unroll
        for (int f = t; f < 2048; f += 256)        // linear 32KB copy
            *(bf16x8*)&Bs[f * 8] = *(const bf16x8*)(srcb + f * 8);
        __syncthreads();

        f32x4 acc[4][4] = {};
        #pragma unroll
        for (int kc = 0; kc < 4; ++kc) {
            const int cs = kc * 32 + kg;
            bf16x8 af[4], bfr[4];
            #pragma unroll
            for (int i = 0; i < 4; ++i) {
                const int ra = wr * 64 + i * 16 + l15;
                af[i] = *(const bf16x8*)&As[ra * 128 + (cs ^ ((ra & 7) << 3))];
                const int rb = wc * 64 + i * 16 + l15;
                bfr[i] = *(const bf16x8*)&Bs[rb * 128 + (cs ^ ((rb & 7) << 3))];
            }
            #pragma unroll
            for (int i = 0; i < 4; ++i)
                #pragma unroll
                for (int j = 0; j < 4; ++j)
                    acc[i][j] = __builtin_amdgcn_mfma_f32_16x16x32_bf16(af[i], bfr[j], acc[i][j], 0, 0, 0);
        }
        __syncthreads();                           // MFMA reads of Bs done

        #pragma unroll
        for (int half = 0; half < 2; ++half) {
            if (wr == half) {
                #pragma unroll
                for (int j = 0; j < 4; ++j) {
                    const int col = wc * 64 + j * 16 + l15;
                    #pragma unroll
                    for (int i = 0; i < 4; ++i) {
                        const int rl = i * 16 + cr0;
                        #pragma unroll
                        for (int q = 0; q < 4; ++q)
                            Cs[(rl + q) * 128 + col] = acc[i][j][q];
                    }
                }
            }
            __syncthreads();
            #pragma unroll
            for (int f = t; f < 2048; f += 256) {
                const int r = f >> 5, c4 = (f & 31) * 4;
                if (n0 + c4 < NVOCAB) {
                    const f32x4 v = *(const f32x4*)&Cs[r * 128 + c4];
                    *(f32x4*)(C + (size_t)(m0 + half * 64 + r) * NVOCAB + n0 + c4) = v;
                }
            }
            __syncthreads();
        }
    }
}

extern "C" void kernel_launch(void* const* d_in, const int* in_sizes, int n_in,
                              void* d_out, int out_size, void* d_ws, size_t ws_size,
                              hipStream_t stream) {
    const int*   x   = (const int*)d_in[0];
    const int*   ei  = (const int*)d_in[1];
    const float* emb = (const float*)d_in[3];
    const float* Wg  = (const float*)d_in[4];
    const float* Wih = (const float*)d_in[5];
    const float* Whh = (const float*)d_in[6];
    const float* bih = (const float*)d_in[7];
    const float* bhh = (const float*)d_in[8];
    const float* W1  = (const float*)d_in[9];
    const float* b1  = (const float*)d_in[10];
    const float* W2  = (const float*)d_in[11];
    const float* b2  = (const float*)d_in[12];
    const float* qw  = (const float*)d_in[13];
    const float* qb  = (const float*)d_in[14];
    const float* W3  = (const float*)d_in[15];
    const float* b3  = (const float*)d_in[16];
    float* out = (float*)d_out;

    // workspace layout (float offsets); ~66 MB
    float*  ws     = (float*)d_ws;
    ushort* hb     = (ushort*)ws;                  // 6,553,600 bf16 (3,276,800 f)
    ushort* hnew   = (ushort*)(ws + 3276800);      // 6,553,600 bf16
    ushort* Wc     = (ushort*)(ws + 6553600);      // 49,152 bf16 (24,576 f)
    ushort* Whhb   = (ushort*)(ws + 6578176);      // 49,152 bf16 (24,576 f)
    ushort* W2b    = (ushort*)(ws + 6602752);      // 16,384 bf16 (8,192 f)
    ushort* shb    = (ushort*)(ws + 6610944);      // 131,072 bf16 (65,536 f)
    ushort* embswz = (ushort*)(ws + 6676480);      // 12,812,288 bf16 (6,406,144 f)
    int*    cnt    = (int*)(ws + 13082624);        // 51,200
    int*    esrc   = cnt + NNODES;                 // 3,276,800

    hipMemsetAsync(cnt, 0, NNODES * sizeof(int), stream);

    // gather + slot-CSR fill + emb pre-swizzle + Wcomb + Whh/W2 pre-cvt
    prep_kernel<<<11280, 256, 0, stream>>>(x, emb, hb, ei, cnt, esrc, embswz,
                                           Wih, Wg, Wc, Whh, Whhb, W2, W2b);

    // fused agg + GRU (gather-sum in phase-1 stage; hb read-only -> hnew)
    gru_fused<<<400, 512, 0, stream>>>(cnt, esrc, hb, Wc, Whhb, bih, bhh, hnew);

    // fused t2 + attention + sh -> shb (bf16, pre-swizzled)
    attn_sh<<<512, 256, 0, stream>>>(hnew, W1, b1, W2b, qw, qb, b2, W3, b3, shb);

    // out = s_h @ emb^T (2 blocks/CU; 2 tiles/block; pre-swizzled operands)
    gemm_vocab<<<3136, 256, 0, stream>>>(out, shb, embswz);
}

// Round 17
// 315.935 us; speedup vs baseline: 1.3081x; 1.3081x over previous
//
#include <hip/hip_runtime.h>
#include <math.h>

#define NNODES 51200
#define NEDGES 409600
#define NB 1024
#define NODES_PER 50
#define NVOCAB 100000
#define NVPAD 100096
#define SLOTS 64

typedef __attribute__((ext_vector_type(8))) short bf16x8;
typedef __attribute__((ext_vector_type(4))) float f32x4;

__device__ __forceinline__ float sigf(float x) { return 1.0f / (1.0f + __expf(-x)); }

__device__ __forceinline__ ushort f2bf(float x) {   // RTNE f32 -> bf16
    union { float f; unsigned u; } v; v.f = x;
    const unsigned r = v.u + 0x7FFF + ((v.u >> 16) & 1);
    return (ushort)(r >> 16);
}
__device__ __forceinline__ float bf2f(ushort u) {
    union { float f; unsigned u; } v; v.u = ((unsigned)u) << 16; return v.f;
}
__device__ __forceinline__ bf16x8 cvt8(const float* __restrict__ src) {
    const float4 v0 = *(const float4*)src, v1 = *(const float4*)(src + 4);
    bf16x8 p;
    p[0] = (short)f2bf(v0.x); p[1] = (short)f2bf(v0.y);
    p[2] = (short)f2bf(v0.z); p[3] = (short)f2bf(v0.w);
    p[4] = (short)f2bf(v1.x); p[5] = (short)f2bf(v1.y);
    p[6] = (short)f2bf(v1.z); p[7] = (short)f2bf(v1.w);
    return p;
}

// ---------------------------------------------------------------------------
// Mega prep kernel (independent segments):
//  [0,3200)        gather: hb[i] = bf16(emb[x[i]-1])
//  [3200,4800)     slot-CSR fill: esrc[dst*64+pos] = src
//  [4800,11056)    embswz: emb -> bf16, pre-swizzled, pad rows zeroed
//  [11056,11248)   Wc[m][n^swz] = bf16(sum_k Wih[m][k]*Wg[n][k])  (swizzled)
//  [11248,11272)   Whhb: Whh -> bf16 pre-swizzled [384][128]
//  [11272,11280)   W2b:  W2  -> bf16 pre-swizzled [128][128]
// ---------------------------------------------------------------------------
__global__ __launch_bounds__(256)
void prep_kernel(const int* __restrict__ x, const float* __restrict__ emb,
                 ushort* __restrict__ hb, const int* __restrict__ ei,
                 int* __restrict__ cnt, int* __restrict__ esrc,
                 ushort* __restrict__ embswz, const float* __restrict__ Wih,
                 const float* __restrict__ Wg, ushort* __restrict__ Wc,
                 const float* __restrict__ Whh, ushort* __restrict__ Whhb,
                 const float* __restrict__ W2, ushort* __restrict__ W2b) {
    const int bid = blockIdx.x;
    const int t = threadIdx.x;
    if (bid < 3200) {                              // gather
        const int tid = bid * 256 + t;
        const int i = tid >> 4, c8 = (tid & 15) * 8;
        const int idx = x[i] - 1;
        *(bf16x8*)(hb + (size_t)i * 128 + c8) = cvt8(emb + (size_t)idx * 128 + c8);
    } else if (bid < 4800) {                       // slot-CSR fill
        const int e = (bid - 3200) * 256 + t;
        const int dst = ei[NEDGES + e];
        const int pos = atomicAdd(&cnt[dst], 1);
        if (pos < SLOTS) esrc[(size_t)dst * SLOTS + pos] = ei[e];
    } else if (bid < 11056) {                      // embswz
        const int f = (bid - 4800) * 256 + t;      // < NVPAD*16
        const int row = f >> 4, c8 = (f & 15) * 8;
        bf16x8 pk = {0, 0, 0, 0, 0, 0, 0, 0};
        if (row < NVOCAB) pk = cvt8(emb + (size_t)row * 128 + c8);
        *(bf16x8*)&embswz[(size_t)row * 128 + (c8 ^ ((row & 7) << 3))] = pk;
    } else if (bid < 11248) {                      // Wcomb = Wih @ Wg^T, swz
        const int idx = (bid - 11056) * 256 + t;   // < 49152
        const int mrow = idx >> 7, n = idx & 127;
        const float* wr = Wih + (size_t)mrow * 128;
        const float* gr = Wg + (size_t)n * 128;
        float acc = 0.f;
        #pragma unroll 8
        for (int k = 0; k < 128; ++k)
            acc = fmaf(wr[k], gr[k], acc);
        Wc[mrow * 128 + (n ^ ((mrow & 7) << 3))] = f2bf(acc);
    } else if (bid < 11272) {                      // Whhb (swizzled bf16)
        const int f = (bid - 11248) * 256 + t;     // < 6144
        const int r = f >> 4, c8 = (f & 15) * 8;
        *(bf16x8*)&Whhb[r * 128 + (c8 ^ ((r & 7) << 3))] = cvt8(Whh + (size_t)r * 128 + c8);
    } else {                                       // W2b (swizzled bf16)
        const int f = (bid - 11272) * 256 + t;     // < 2048
        const int r = f >> 4, c8 = (f & 15) * 8;
        *(bf16x8*)&W2b[r * 128 + (c8 ^ ((r & 7) << 3))] = cvt8(W2 + (size_t)r * 128 + c8);
    }
}

// S[i] = sum over in-edges of hb[src]; one wave per node; output PRE-SWIZZLED
// (node is wave-uniform -> XOR permutes 4B slots within the 256B row segment;
// the write stays one coalesced 256B store).
__global__ __launch_bounds__(256)
void agg_kernel(const int* __restrict__ cnt, const int* __restrict__ esrc,
                const ushort* __restrict__ hb, ushort* __restrict__ aggb) {
    const int node = blockIdx.x * 4 + (threadIdx.x >> 6);
    const int l = threadIdx.x & 63;
    int cn = cnt[node]; if (cn > SLOTS) cn = SLOTS;
    const int* es = esrc + (size_t)node * SLOTS;
    float ax = 0.f, ay = 0.f;
    for (int j = 0; j < cn; ++j) {
        const int src = es[j];
        const unsigned u = *(const unsigned*)(hb + (size_t)src * 128 + l * 2);
        ax += bf2f((ushort)(u & 0xffff));
        ay += bf2f((ushort)(u >> 16));
    }
    const unsigned o = (unsigned)f2bf(ax) | ((unsigned)f2bf(ay) << 16);
    *(unsigned*)(aggb + (size_t)node * 128 + ((l * 2) ^ ((node & 7) << 3))) = o;
}

// ---------------------------------------------------------------------------
// Fully fused GRU on bf16 h (in place): 400 blocks x 512 thr, 128 rows each.
// A-stages are linear copies (aggb pre-swizzled); B-stages linear (Wc/Whhb).
// ---------------------------------------------------------------------------
__global__ __launch_bounds__(512)
void gru_fused(const ushort* __restrict__ aggb, const ushort* __restrict__ Wc,
               const ushort* __restrict__ Whhb, const float* __restrict__ bih,
               const float* __restrict__ bhh, ushort* __restrict__ hb) {
    __shared__ ushort As[128 * 128];
    __shared__ ushort Bs[384 * 128];
    const int m0 = blockIdx.x * 128;
    const int t = threadIdx.x;
    const int lane = t & 63, wid = t >> 6;
    const int l15 = lane & 15, kg = (lane >> 4) * 8;

    // ---- phase 1: gi = S @ Wcomb^T (both stages linear) ----
    #pragma unroll
    for (int f = t; f < 2048; f += 512)
        *(bf16x8*)&As[f * 8] = *(const bf16x8*)(aggb + (size_t)m0 * 128 + f * 8);
    #pragma unroll
    for (int f = t; f < 6144; f += 512)
        *(bf16x8*)&Bs[f * 8] = *(const bf16x8*)(Wc + (size_t)f * 8);
    __syncthreads();

    f32x4 gi[24] = {};
    #pragma unroll
    for (int kc = 0; kc < 4; ++kc) {
        const int cs = kc * 32 + kg;
        const int ra = wid * 16 + l15;
        const bf16x8 af = *(const bf16x8*)&As[ra * 128 + (cs ^ ((ra & 7) << 3))];
        #pragma unroll
        for (int j = 0; j < 24; ++j) {
            const int rb = j * 16 + l15;
            const bf16x8 bfr = *(const bf16x8*)&Bs[rb * 128 + (cs ^ ((rb & 7) << 3))];
            gi[j] = __builtin_amdgcn_mfma_f32_16x16x32_bf16(af, bfr, gi[j], 0, 0, 0);
        }
    }
    __syncthreads();

    // ---- phase 2: gh = h @ Whh^T (As = bf16 h, kept for epilogue) ----
    #pragma unroll
    for (int f = t; f < 2048; f += 512) {
        const int r = f >> 4, c8 = (f & 15) * 8;
        const bf16x8 pk = *(const bf16x8*)(hb + (size_t)(m0 + r) * 128 + c8);
        *(bf16x8*)&As[r * 128 + (c8 ^ ((r & 7) << 3))] = pk;
    }
    #pragma unroll
    for (int f = t; f < 6144; f += 512)
        *(bf16x8*)&Bs[f * 8] = *(const bf16x8*)(Whhb + (size_t)f * 8);
    __syncthreads();

    f32x4 gh[24] = {};
    #pragma unroll
    for (int kc = 0; kc < 4; ++kc) {
        const int cs = kc * 32 + kg;
        const int ra = wid * 16 + l15;
        const bf16x8 af = *(const bf16x8*)&As[ra * 128 + (cs ^ ((ra & 7) << 3))];
        #pragma unroll
        for (int j = 0; j < 24; ++j) {
            const int rb = j * 16 + l15;
            const bf16x8 bfr = *(const bf16x8*)&Bs[rb * 128 + (cs ^ ((rb & 7) << 3))];
            gh[j] = __builtin_amdgcn_mfma_f32_16x16x32_bf16(af, bfr, gh[j], 0, 0, 0);
        }
    }

    // ---- epilogue: gates + ReLU; hv from As; result back into As ----
    const int lr0 = wid * 16 + (lane >> 4) * 4;
    #pragma unroll
    for (int j = 0; j < 8; ++j) {
        const int col = j * 16 + l15;
        const float bir = bih[col], biz = bih[128 + col], bin = bih[256 + col];
        const float bhr = bhh[col], bhz = bhh[128 + col], bhn = bhh[256 + col];
        #pragma unroll
        for (int q = 0; q < 4; ++q) {
            const int lr = lr0 + q;
            const int adr = lr * 128 + (col ^ ((lr & 7) << 3));
            const float hv = bf2f(As[adr]);
            const float r_ = sigf(gi[j][q] + bir + gh[j][q] + bhr);
            const float z  = sigf(gi[j + 8][q] + biz + gh[j + 8][q] + bhz);
            const float ng = tanhf(gi[j + 16][q] + bin + r_ * (gh[j + 16][q] + bhn));
            As[adr] = f2bf(fmaxf((1.f - z) * ng + z * hv, 0.f));
        }
    }
    __syncthreads();
    #pragma unroll
    for (int f = t; f < 2048; f += 512) {
        const int r = f >> 4, c8 = (f & 15) * 8;
        *(bf16x8*)(hb + (size_t)(m0 + r) * 128 + c8) =
            *(const bf16x8*)&As[r * 128 + (c8 ^ ((r & 7) << 3))];
    }
}

// ---------------------------------------------------------------------------
// Fused t2-GEMM + attention + sh: 512 blocks x 256 thr, 2 sessions each.
// ---------------------------------------------------------------------------
__global__ __launch_bounds__(256)
void attn_sh(const ushort* __restrict__ hb, const float* __restrict__ W1,
             const float* __restrict__ b1, const ushort* __restrict__ W2b,
             const float* __restrict__ qw, const float* __restrict__ qbp,
             const float* __restrict__ b2, const float* __restrict__ W3,
             const float* __restrict__ b3, ushort* __restrict__ shb) {
    __shared__ ushort As[128 * 128];     // h tile bf16 (swizzled)
    __shared__ ushort Bs[128 * 128];     // W2 bf16, then t2T bf16 [d][row]
    __shared__ float t1s[2][128];
    __shared__ float qws[128];
    __shared__ float apar[2][2][64];
    __shared__ float alph[2][64];
    __shared__ float sgs[2][128];
    const int m0 = blockIdx.x * 100;
    const int t = threadIdx.x;
    const int lane = t & 63, wid = t >> 6;
    const int wr = wid >> 1, wc = wid & 1;
    const int l15 = lane & 15, kg = (lane >> 4) * 8;
    const int cr0 = (lane >> 4) * 4;

    #pragma unroll
    for (int f = t; f < 2048; f += 256) {
        const int r = f >> 4, c8 = (f & 15) * 8;
        int gr = m0 + r; if (gr > NNODES - 1) gr = NNODES - 1;   // clamp tail
        *(bf16x8*)&As[r * 128 + (c8 ^ ((r & 7) << 3))] =
            *(const bf16x8*)(hb + (size_t)gr * 128 + c8);
        *(bf16x8*)&Bs[f * 8] = *(const bf16x8*)(W2b + (size_t)f * 8);
    }
    if (t < 128) qws[t] = qw[t];
    __syncthreads();

    // t2 = h @ W2^T
    f32x4 acc[4][4] = {};
    #pragma unroll
    for (int kc = 0; kc < 4; ++kc) {
        const int cs = kc * 32 + kg;
        bf16x8 af[4], bfr[4];
        #pragma unroll
        for (int i = 0; i < 4; ++i) {
            const int ra = wr * 64 + i * 16 + l15;
            af[i] = *(const bf16x8*)&As[ra * 128 + (cs ^ ((ra & 7) << 3))];
            const int rb = wc * 64 + i * 16 + l15;
            bfr[i] = *(const bf16x8*)&Bs[rb * 128 + (cs ^ ((rb & 7) << 3))];
        }
        #pragma unroll
        for (int i = 0; i < 4; ++i)
            #pragma unroll
            for (int j = 0; j < 4; ++j)
                acc[i][j] = __builtin_amdgcn_mfma_f32_16x16x32_bf16(af[i], bfr[j], acc[i][j], 0, 0, 0);
    }
    __syncthreads();                               // MFMA reads of Bs done

    // t2T (bf16, swizzled) overlays Bs: addr = d*128 + (row ^ ((d&7)<<3))
    #pragma unroll
    for (int j = 0; j < 4; ++j) {
        const int col = wc * 64 + j * 16 + l15;
        const int csw = (col & 7) << 3;
        #pragma unroll
        for (int i = 0; i < 4; ++i) {
            const int row = wr * 64 + i * 16 + cr0;
            #pragma unroll
            for (int q = 0; q < 4; ++q)
                Bs[col * 128 + ((row + q) ^ csw)] = f2bf(acc[i][j][q]);
        }
    }

    // t1[d] = W1[d]·vn + b1[d] + b2[d]
    const int sess = wid >> 1, half = wid & 1;
    const int d = half * 64 + lane;
    const int vrow = sess * 50 + 49;
    const int vsw = (vrow & 7) << 3;
    float t1v = b1[d] + b2[d];
    const float* w1r = W1 + (size_t)d * 128;
    #pragma unroll 8
    for (int k = 0; k < 128; k += 4) {
        const float4 w = *(const float4*)(w1r + k);
        t1v += w.x * bf2f(As[vrow * 128 + ((k + 0) ^ vsw)])
             + w.y * bf2f(As[vrow * 128 + ((k + 1) ^ vsw)])
             + w.z * bf2f(As[vrow * 128 + ((k + 2) ^ vsw)])
             + w.w * bf2f(As[vrow * 128 + ((k + 3) ^ vsw)]);
    }
    t1s[sess][d] = t1v;
    __syncthreads();

    // alphas: lane = node (l<50), sum over this half's 64 dims
    float p = 0.f;
    if (lane < 50) {
        const int row = sess * 50 + lane;
        const int d0 = half * 64;
        #pragma unroll 8
        for (int dd = d0; dd < d0 + 64; ++dd)
            p += qws[dd] * sigf(t1s[sess][dd] + bf2f(Bs[dd * 128 + (row ^ ((dd & 7) << 3))]));
    }
    apar[sess][half][lane] = p;
    __syncthreads();
    if (half == 0 && lane < 50)
        alph[sess][lane] = apar[sess][0][lane] + apar[sess][1][lane] + qbp[0];
    __syncthreads();

    // sg[d] = sum_i alpha_i * h[i][d]  (kept in LDS)
    float sacc = 0.f;
    #pragma unroll 10
    for (int i = 0; i < 50; ++i) {
        const int row = sess * 50 + i;
        sacc += alph[sess][i] * bf2f(As[row * 128 + (d ^ ((row & 7) << 3))]);
    }
    sgs[sess][d] = sacc;
    __syncthreads();

    // sh[d] = W3[d] · [vn; sg] + b3[d]  -> shb bf16 pre-swizzled
    float shacc = b3[d];
    const float* w3r = W3 + (size_t)d * 256;
    #pragma unroll 8
    for (int k = 0; k < 128; k += 4) {
        const float4 w = *(const float4*)(w3r + k);
        shacc += w.x * bf2f(As[vrow * 128 + ((k + 0) ^ vsw)])
               + w.y * bf2f(As[vrow * 128 + ((k + 1) ^ vsw)])
               + w.z * bf2f(As[vrow * 128 + ((k + 2) ^ vsw)])
               + w.w * bf2f(As[vrow * 128 + ((k + 3) ^ vsw)]);
    }
    #pragma unroll 8
    for (int k = 0; k < 128; k += 4) {
        const float4 w = *(const float4*)(w3r + 128 + k);
        shacc += w.x * sgs[sess][k] + w.y * sgs[sess][k + 1]
               + w.z * sgs[sess][k + 2] + w.w * sgs[sess][k + 3];
    }
    const int orow = blockIdx.x * 2 + sess;
    shb[(size_t)orow * 128 + (d ^ ((orow & 7) << 3))] = f2bf(shacc);
}

// ---------------------------------------------------------------------------
// Vocab GEMM: out = sh @ emb^T. 256 thr (4 waves 2x2), LDS 64 KB -> 2
// blocks/CU. A staged once (linear from shb); 2 n-tiles/block.
// Grid 3136 = 8 xcd x 8 mt x 49 g; grp >= 391 exits early.
// ---------------------------------------------------------------------------
__global__ __launch_bounds__(256)
void gemm_vocab(float* __restrict__ C, const ushort* __restrict__ Ab,
                const ushort* __restrict__ Bswz) {
    __shared__ ushort As[128 * 128];
    __shared__ ushort Bs[128 * 128];
    float* Cs = (float*)Bs;                        // [64][128] f32 overlay
    const int id = blockIdx.x;
    const int xcd = id & 7, loc = id >> 3;
    const int mt = loc & 7, g = loc >> 3;          // mt 0..7, g 0..48
    const int grp = xcd * 49 + g;                  // 0..391
    if (grp * 256 >= NVOCAB) return;               // block-uniform early out
    const int m0 = mt * 128;
    const int t = threadIdx.x;
    const int lane = t & 63, wid = t >> 6;
    const int wr = wid >> 1, wc = wid & 1;
    const int l15 = lane & 15, kg = (lane >> 4) * 8;
    const int cr0 = (lane >> 4) * 4;

    // stage A once (linear; shb pre-swizzled)
    #pragma unroll
    for (int f = t; f < 2048; f += 256)
        *(bf16x8*)&As[f * 8] = *(const bf16x8*)(Ab + (size_t)m0 * 128 + f * 8);

    for (int it = 0; it < 2; ++it) {
        const int n0 = (grp * 2 + it) * 128;
        if (n0 >= NVOCAB) break;                   // block-uniform
        __syncthreads();                           // prev repack reads done
        const ushort* srcb = Bswz + (size_t)n0 * 128;
        #pragma unroll
        for (int f = t; f < 2048; f += 256)        // linear 32KB copy
            *(bf16x8*)&Bs[f * 8] = *(const bf16x8*)(srcb + f * 8);
        __syncthreads();

        f32x4 acc[4][4] = {};
        #pragma unroll
        for (int kc = 0; kc < 4; ++kc) {
            const int cs = kc * 32 + kg;
            bf16x8 af[4], bfr[4];
            #pragma unroll
            for (int i = 0; i < 4; ++i) {
                const int ra = wr * 64 + i * 16 + l15;
                af[i] = *(const bf16x8*)&As[ra * 128 + (cs ^ ((ra & 7) << 3))];
                const int rb = wc * 64 + i * 16 + l15;
                bfr[i] = *(const bf16x8*)&Bs[rb * 128 + (cs ^ ((rb & 7) << 3))];
            }
            #pragma unroll
            for (int i = 0; i < 4; ++i)
                #pragma unroll
                for (int j = 0; j < 4; ++j)
                    acc[i][j] = __builtin_amdgcn_mfma_f32_16x16x32_bf16(af[i], bfr[j], acc[i][j], 0, 0, 0);
        }
        __syncthreads();                           // MFMA reads of Bs done

        #pragma unroll
        for (int half = 0; half < 2; ++half) {
            if (wr == half) {
                #pragma unroll
                for (int j = 0; j < 4; ++j) {
                    const int col = wc * 64 + j * 16 + l15;
                    #pragma unroll
                    for (int i = 0; i < 4; ++i) {
                        const int rl = i * 16 + cr0;
                        #pragma unroll
                        for (int q = 0; q < 4; ++q)
                            Cs[(rl + q) * 128 + col] = acc[i][j][q];
                    }
                }
            }
            __syncthreads();
            #pragma unroll
            for (int f = t; f < 2048; f += 256) {
                const int r = f >> 5, c4 = (f & 31) * 4;
                if (n0 + c4 < NVOCAB) {
                    const f32x4 v = *(const f32x4*)&Cs[r * 128 + c4];
                    *(f32x4*)(C + (size_t)(m0 + half * 64 + r) * NVOCAB + n0 + c4) = v;
                }
            }
            __syncthreads();
        }
    }
}

extern "C" void kernel_launch(void* const* d_in, const int* in_sizes, int n_in,
                              void* d_out, int out_size, void* d_ws, size_t ws_size,
                              hipStream_t stream) {
    const int*   x   = (const int*)d_in[0];
    const int*   ei  = (const int*)d_in[1];
    const float* emb = (const float*)d_in[3];
    const float* Wg  = (const float*)d_in[4];
    const float* Wih = (const float*)d_in[5];
    const float* Whh = (const float*)d_in[6];
    const float* bih = (const float*)d_in[7];
    const float* bhh = (const float*)d_in[8];
    const float* W1  = (const float*)d_in[9];
    const float* b1  = (const float*)d_in[10];
    const float* W2  = (const float*)d_in[11];
    const float* b2  = (const float*)d_in[12];
    const float* qw  = (const float*)d_in[13];
    const float* qb  = (const float*)d_in[14];
    const float* W3  = (const float*)d_in[15];
    const float* b3  = (const float*)d_in[16];
    float* out = (float*)d_out;

    // workspace layout (float offsets); ~66 MB
    float*  ws     = (float*)d_ws;
    ushort* hb     = (ushort*)ws;                  // 6,553,600 bf16 (3,276,800 f)
    ushort* aggb   = (ushort*)(ws + 3276800);      // 6,553,600 bf16 (pre-swizzled)
    ushort* Wc     = (ushort*)(ws + 6553600);      // 49,152 bf16 (24,576 f)
    ushort* Whhb   = (ushort*)(ws + 6578176);      // 49,152 bf16 (24,576 f)
    ushort* W2b    = (ushort*)(ws + 6602752);      // 16,384 bf16 (8,192 f)
    ushort* shb    = (ushort*)(ws + 6610944);      // 131,072 bf16 (65,536 f)
    ushort* embswz = (ushort*)(ws + 6676480);      // 12,812,288 bf16 (6,406,144 f)
    int*    cnt    = (int*)(ws + 13082624);        // 51,200
    int*    esrc   = cnt + NNODES;                 // 3,276,800

    hipMemsetAsync(cnt, 0, NNODES * sizeof(int), stream);

    // gather + slot-CSR fill + emb pre-swizzle + Wcomb + Whh/W2 pre-cvt
    prep_kernel<<<11280, 256, 0, stream>>>(x, emb, hb, ei, cnt, esrc, embswz,
                                           Wih, Wg, Wc, Whh, Whhb, W2, W2b);

    // gather-sum S = sum hb[src] (deep TLP; writes pre-swizzled aggb)
    agg_kernel<<<12800, 256, 0, stream>>>(cnt, esrc, hb, aggb);

    // fused GRU (gi/gh in registers; h bf16 in place)
    gru_fused<<<400, 512, 0, stream>>>(aggb, Wc, Whhb, bih, bhh, hb);

    // fused t2 + attention + sh -> shb (bf16, pre-swizzled)
    attn_sh<<<512, 256, 0, stream>>>(hb, W1, b1, W2b, qw, qb, b2, W3, b3, shb);

    // out = s_h @ emb^T (2 blocks/CU; 2 tiles/block; pre-swizzled operands)
    gemm_vocab<<<3136, 256, 0, stream>>>(out, shb, embswz);
}

// Round 18
// 310.311 us; speedup vs baseline: 1.3318x; 1.0181x over previous
//
#include <hip/hip_runtime.h>
#include <math.h>

#define NNODES 51200
#define NEDGES 409600
#define NB 1024
#define NODES_PER 50
#define NVOCAB 100000
#define NVPAD 100096
#define SLOTS 64

typedef __attribute__((ext_vector_type(8))) short bf16x8;
typedef __attribute__((ext_vector_type(4))) float f32x4;

__device__ __forceinline__ float sigf(float x) { return 1.0f / (1.0f + __expf(-x)); }

__device__ __forceinline__ ushort f2bf(float x) {   // RTNE f32 -> bf16
    union { float f; unsigned u; } v; v.f = x;
    const unsigned r = v.u + 0x7FFF + ((v.u >> 16) & 1);
    return (ushort)(r >> 16);
}
__device__ __forceinline__ float bf2f(ushort u) {
    union { float f; unsigned u; } v; v.u = ((unsigned)u) << 16; return v.f;
}
__device__ __forceinline__ bf16x8 cvt8(const float* __restrict__ src) {
    const float4 v0 = *(const float4*)src, v1 = *(const float4*)(src + 4);
    bf16x8 p;
    p[0] = (short)f2bf(v0.x); p[1] = (short)f2bf(v0.y);
    p[2] = (short)f2bf(v0.z); p[3] = (short)f2bf(v0.w);
    p[4] = (short)f2bf(v1.x); p[5] = (short)f2bf(v1.y);
    p[6] = (short)f2bf(v1.z); p[7] = (short)f2bf(v1.w);
    return p;
}

// ---------------------------------------------------------------------------
// Mega prep kernel (independent segments):
//  [0,3200)        gather: hb[i] = bf16(emb[x[i]-1])
//  [3200,4800)     slot-CSR fill: esrc[dst*64+pos] = src
//  [4800,11056)    embswz: emb -> bf16, pre-swizzled, pad rows zeroed
//  [11056,11248)   Wc[m][n^swz] = bf16(sum_k Wih[m][k]*Wg[n][k])  (swizzled)
//  [11248,11272)   Whhb: Whh -> bf16 pre-swizzled [384][128]
//  [11272,11280)   W2b:  W2  -> bf16 pre-swizzled [128][128]
// ---------------------------------------------------------------------------
__global__ __launch_bounds__(256)
void prep_kernel(const int* __restrict__ x, const float* __restrict__ emb,
                 ushort* __restrict__ hb, const int* __restrict__ ei,
                 int* __restrict__ cnt, int* __restrict__ esrc,
                 ushort* __restrict__ embswz, const float* __restrict__ Wih,
                 const float* __restrict__ Wg, ushort* __restrict__ Wc,
                 const float* __restrict__ Whh, ushort* __restrict__ Whhb,
                 const float* __restrict__ W2, ushort* __restrict__ W2b) {
    const int bid = blockIdx.x;
    const int t = threadIdx.x;
    if (bid < 3200) {                              // gather
        const int tid = bid * 256 + t;
        const int i = tid >> 4, c8 = (tid & 15) * 8;
        const int idx = x[i] - 1;
        *(bf16x8*)(hb + (size_t)i * 128 + c8) = cvt8(emb + (size_t)idx * 128 + c8);
    } else if (bid < 4800) {                       // slot-CSR fill
        const int e = (bid - 3200) * 256 + t;
        const int dst = ei[NEDGES + e];
        const int pos = atomicAdd(&cnt[dst], 1);
        if (pos < SLOTS) esrc[(size_t)dst * SLOTS + pos] = ei[e];
    } else if (bid < 11056) {                      // embswz
        const int f = (bid - 4800) * 256 + t;      // < NVPAD*16
        const int row = f >> 4, c8 = (f & 15) * 8;
        bf16x8 pk = {0, 0, 0, 0, 0, 0, 0, 0};
        if (row < NVOCAB) pk = cvt8(emb + (size_t)row * 128 + c8);
        *(bf16x8*)&embswz[(size_t)row * 128 + (c8 ^ ((row & 7) << 3))] = pk;
    } else if (bid < 11248) {                      // Wcomb = Wih @ Wg^T, swz
        const int idx = (bid - 11056) * 256 + t;   // < 49152
        const int mrow = idx >> 7, n = idx & 127;
        const float* wr = Wih + (size_t)mrow * 128;
        const float* gr = Wg + (size_t)n * 128;
        float acc = 0.f;
        #pragma unroll 8
        for (int k = 0; k < 128; ++k)
            acc = fmaf(wr[k], gr[k], acc);
        Wc[mrow * 128 + (n ^ ((mrow & 7) << 3))] = f2bf(acc);
    } else if (bid < 11272) {                      // Whhb (swizzled bf16)
        const int f = (bid - 11248) * 256 + t;     // < 6144
        const int r = f >> 4, c8 = (f & 15) * 8;
        *(bf16x8*)&Whhb[r * 128 + (c8 ^ ((r & 7) << 3))] = cvt8(Whh + (size_t)r * 128 + c8);
    } else {                                       // W2b (swizzled bf16)
        const int f = (bid - 11272) * 256 + t;     // < 2048
        const int r = f >> 4, c8 = (f & 15) * 8;
        *(bf16x8*)&W2b[r * 128 + (c8 ^ ((r & 7) << 3))] = cvt8(W2 + (size_t)r * 128 + c8);
    }
}

// S[i] = sum over in-edges of hb[src]; one wave per node; output PRE-SWIZZLED
__global__ __launch_bounds__(256)
void agg_kernel(const int* __restrict__ cnt, const int* __restrict__ esrc,
                const ushort* __restrict__ hb, ushort* __restrict__ aggb) {
    const int node = blockIdx.x * 4 + (threadIdx.x >> 6);
    const int l = threadIdx.x & 63;
    int cn = cnt[node]; if (cn > SLOTS) cn = SLOTS;
    const int* es = esrc + (size_t)node * SLOTS;
    float ax = 0.f, ay = 0.f;
    for (int j = 0; j < cn; ++j) {
        const int src = es[j];
        const unsigned u = *(const unsigned*)(hb + (size_t)src * 128 + l * 2);
        ax += bf2f((ushort)(u & 0xffff));
        ay += bf2f((ushort)(u >> 16));
    }
    const unsigned o = (unsigned)f2bf(ax) | ((unsigned)f2bf(ay) << 16);
    *(unsigned*)(aggb + (size_t)node * 128 + ((l * 2) ^ ((node & 7) << 3))) = o;
}

// ---------------------------------------------------------------------------
// Fully fused GRU on bf16 h (in place): 400 blocks x 512 thr, 128 rows each.
// ---------------------------------------------------------------------------
__global__ __launch_bounds__(512)
void gru_fused(const ushort* __restrict__ aggb, const ushort* __restrict__ Wc,
               const ushort* __restrict__ Whhb, const float* __restrict__ bih,
               const float* __restrict__ bhh, ushort* __restrict__ hb) {
    __shared__ ushort As[128 * 128];
    __shared__ ushort Bs[384 * 128];
    const int m0 = blockIdx.x * 128;
    const int t = threadIdx.x;
    const int lane = t & 63, wid = t >> 6;
    const int l15 = lane & 15, kg = (lane >> 4) * 8;

    // ---- phase 1: gi = S @ Wcomb^T (both stages linear) ----
    #pragma unroll
    for (int f = t; f < 2048; f += 512)
        *(bf16x8*)&As[f * 8] = *(const bf16x8*)(aggb + (size_t)m0 * 128 + f * 8);
    #pragma unroll
    for (int f = t; f < 6144; f += 512)
        *(bf16x8*)&Bs[f * 8] = *(const bf16x8*)(Wc + (size_t)f * 8);
    __syncthreads();

    f32x4 gi[24] = {};
    #pragma unroll
    for (int kc = 0; kc < 4; ++kc) {
        const int cs = kc * 32 + kg;
        const int ra = wid * 16 + l15;
        const bf16x8 af = *(const bf16x8*)&As[ra * 128 + (cs ^ ((ra & 7) << 3))];
        #pragma unroll
        for (int j = 0; j < 24; ++j) {
            const int rb = j * 16 + l15;
            const bf16x8 bfr = *(const bf16x8*)&Bs[rb * 128 + (cs ^ ((rb & 7) << 3))];
            gi[j] = __builtin_amdgcn_mfma_f32_16x16x32_bf16(af, bfr, gi[j], 0, 0, 0);
        }
    }
    __syncthreads();

    // ---- phase 2: gh = h @ Whh^T (As = bf16 h, kept for epilogue) ----
    #pragma unroll
    for (int f = t; f < 2048; f += 512) {
        const int r = f >> 4, c8 = (f & 15) * 8;
        const bf16x8 pk = *(const bf16x8*)(hb + (size_t)(m0 + r) * 128 + c8);
        *(bf16x8*)&As[r * 128 + (c8 ^ ((r & 7) << 3))] = pk;
    }
    #pragma unroll
    for (int f = t; f < 6144; f += 512)
        *(bf16x8*)&Bs[f * 8] = *(const bf16x8*)(Whhb + (size_t)f * 8);
    __syncthreads();

    f32x4 gh[24] = {};
    #pragma unroll
    for (int kc = 0; kc < 4; ++kc) {
        const int cs = kc * 32 + kg;
        const int ra = wid * 16 + l15;
        const bf16x8 af = *(const bf16x8*)&As[ra * 128 + (cs ^ ((ra & 7) << 3))];
        #pragma unroll
        for (int j = 0; j < 24; ++j) {
            const int rb = j * 16 + l15;
            const bf16x8 bfr = *(const bf16x8*)&Bs[rb * 128 + (cs ^ ((rb & 7) << 3))];
            gh[j] = __builtin_amdgcn_mfma_f32_16x16x32_bf16(af, bfr, gh[j], 0, 0, 0);
        }
    }

    // ---- epilogue: gates + ReLU; hv from As; result back into As ----
    const int lr0 = wid * 16 + (lane >> 4) * 4;
    #pragma unroll
    for (int j = 0; j < 8; ++j) {
        const int col = j * 16 + l15;
        const float bir = bih[col], biz = bih[128 + col], bin = bih[256 + col];
        const float bhr = bhh[col], bhz = bhh[128 + col], bhn = bhh[256 + col];
        #pragma unroll
        for (int q = 0; q < 4; ++q) {
            const int lr = lr0 + q;
            const int adr = lr * 128 + (col ^ ((lr & 7) << 3));
            const float hv = bf2f(As[adr]);
            const float r_ = sigf(gi[j][q] + bir + gh[j][q] + bhr);
            const float z  = sigf(gi[j + 8][q] + biz + gh[j + 8][q] + bhz);
            const float ng = tanhf(gi[j + 16][q] + bin + r_ * (gh[j + 16][q] + bhn));
            As[adr] = f2bf(fmaxf((1.f - z) * ng + z * hv, 0.f));
        }
    }
    __syncthreads();
    #pragma unroll
    for (int f = t; f < 2048; f += 512) {
        const int r = f >> 4, c8 = (f & 15) * 8;
        *(bf16x8*)(hb + (size_t)(m0 + r) * 128 + c8) =
            *(const bf16x8*)&As[r * 128 + (c8 ^ ((r & 7) << 3))];
    }
}

// ---------------------------------------------------------------------------
// Fused t2-GEMM + attention + sh: 512 blocks x 256 thr, 2 sessions each.
// ---------------------------------------------------------------------------
__global__ __launch_bounds__(256)
void attn_sh(const ushort* __restrict__ hb, const float* __restrict__ W1,
             const float* __restrict__ b1, const ushort* __restrict__ W2b,
             const float* __restrict__ qw, const float* __restrict__ qbp,
             const float* __restrict__ b2, const float* __restrict__ W3,
             const float* __restrict__ b3, ushort* __restrict__ shb) {
    __shared__ ushort As[128 * 128];     // h tile bf16 (swizzled)
    __shared__ ushort Bs[128 * 128];     // W2 bf16, then t2T bf16 [d][row]
    __shared__ float t1s[2][128];
    __shared__ float qws[128];
    __shared__ float apar[2][2][64];
    __shared__ float alph[2][64];
    __shared__ float sgs[2][128];
    const int m0 = blockIdx.x * 100;
    const int t = threadIdx.x;
    const int lane = t & 63, wid = t >> 6;
    const int wr = wid >> 1, wc = wid & 1;
    const int l15 = lane & 15, kg = (lane >> 4) * 8;
    const int cr0 = (lane >> 4) * 4;

    #pragma unroll
    for (int f = t; f < 2048; f += 256) {
        const int r = f >> 4, c8 = (f & 15) * 8;
        int gr = m0 + r; if (gr > NNODES - 1) gr = NNODES - 1;   // clamp tail
        *(bf16x8*)&As[r * 128 + (c8 ^ ((r & 7) << 3))] =
            *(const bf16x8*)(hb + (size_t)gr * 128 + c8);
        *(bf16x8*)&Bs[f * 8] = *(const bf16x8*)(W2b + (size_t)f * 8);
    }
    if (t < 128) qws[t] = qw[t];
    __syncthreads();

    // t2 = h @ W2^T
    f32x4 acc[4][4] = {};
    #pragma unroll
    for (int kc = 0; kc < 4; ++kc) {
        const int cs = kc * 32 + kg;
        bf16x8 af[4], bfr[4];
        #pragma unroll
        for (int i = 0; i < 4; ++i) {
            const int ra = wr * 64 + i * 16 + l15;
            af[i] = *(const bf16x8*)&As[ra * 128 + (cs ^ ((ra & 7) << 3))];
            const int rb = wc * 64 + i * 16 + l15;
            bfr[i] = *(const bf16x8*)&Bs[rb * 128 + (cs ^ ((rb & 7) << 3))];
        }
        #pragma unroll
        for (int i = 0; i < 4; ++i)
            #pragma unroll
            for (int j = 0; j < 4; ++j)
                acc[i][j] = __builtin_amdgcn_mfma_f32_16x16x32_bf16(af[i], bfr[j], acc[i][j], 0, 0, 0);
    }
    __syncthreads();                               // MFMA reads of Bs done

    // t2T (bf16, swizzled) overlays Bs: addr = d*128 + (row ^ ((d&7)<<3))
    #pragma unroll
    for (int j = 0; j < 4; ++j) {
        const int col = wc * 64 + j * 16 + l15;
        const int csw = (col & 7) << 3;
        #pragma unroll
        for (int i = 0; i < 4; ++i) {
            const int row = wr * 64 + i * 16 + cr0;
            #pragma unroll
            for (int q = 0; q < 4; ++q)
                Bs[col * 128 + ((row + q) ^ csw)] = f2bf(acc[i][j][q]);
        }
    }

    // t1[d] = W1[d]·vn + b1[d] + b2[d]
    const int sess = wid >> 1, half = wid & 1;
    const int d = half * 64 + lane;
    const int vrow = sess * 50 + 49;
    const int vsw = (vrow & 7) << 3;
    float t1v = b1[d] + b2[d];
    const float* w1r = W1 + (size_t)d * 128;
    #pragma unroll 8
    for (int k = 0; k < 128; k += 4) {
        const float4 w = *(const float4*)(w1r + k);
        t1v += w.x * bf2f(As[vrow * 128 + ((k + 0) ^ vsw)])
             + w.y * bf2f(As[vrow * 128 + ((k + 1) ^ vsw)])
             + w.z * bf2f(As[vrow * 128 + ((k + 2) ^ vsw)])
             + w.w * bf2f(As[vrow * 128 + ((k + 3) ^ vsw)]);
    }
    t1s[sess][d] = t1v;
    __syncthreads();

    // alphas: lane = node (l<50), sum over this half's 64 dims
    float p = 0.f;
    if (lane < 50) {
        const int row = sess * 50 + lane;
        const int d0 = half * 64;
        #pragma unroll 8
        for (int dd = d0; dd < d0 + 64; ++dd)
            p += qws[dd] * sigf(t1s[sess][dd] + bf2f(Bs[dd * 128 + (row ^ ((dd & 7) << 3))]));
    }
    apar[sess][half][lane] = p;
    __syncthreads();
    if (half == 0 && lane < 50)
        alph[sess][lane] = apar[sess][0][lane] + apar[sess][1][lane] + qbp[0];
    __syncthreads();

    // sg[d] = sum_i alpha_i * h[i][d]  (kept in LDS)
    float sacc = 0.f;
    #pragma unroll 10
    for (int i = 0; i < 50; ++i) {
        const int row = sess * 50 + i;
        sacc += alph[sess][i] * bf2f(As[row * 128 + (d ^ ((row & 7) << 3))]);
    }
    sgs[sess][d] = sacc;
    __syncthreads();

    // sh[d] = W3[d] · [vn; sg] + b3[d]  -> shb bf16 pre-swizzled
    float shacc = b3[d];
    const float* w3r = W3 + (size_t)d * 256;
    #pragma unroll 8
    for (int k = 0; k < 128; k += 4) {
        const float4 w = *(const float4*)(w3r + k);
        shacc += w.x * bf2f(As[vrow * 128 + ((k + 0) ^ vsw)])
               + w.y * bf2f(As[vrow * 128 + ((k + 1) ^ vsw)])
               + w.z * bf2f(As[vrow * 128 + ((k + 2) ^ vsw)])
               + w.w * bf2f(As[vrow * 128 + ((k + 3) ^ vsw)]);
    }
    #pragma unroll 8
    for (int k = 0; k < 128; k += 4) {
        const float4 w = *(const float4*)(w3r + 128 + k);
        shacc += w.x * sgs[sess][k] + w.y * sgs[sess][k + 1]
               + w.z * sgs[sess][k + 2] + w.w * sgs[sess][k + 3];
    }
    const int orow = blockIdx.x * 2 + sess;
    shb[(size_t)orow * 128 + (d ^ ((orow & 7) << 3))] = f2bf(shacc);
}

// ---------------------------------------------------------------------------
// Vocab GEMM v4: ONE 128x128 tile per block, stores at kernel retire.
// Grid 6272 = 8 xcd x 8 mt x 98 g; grp = xcd*98+g in [0,784), early-out >=782.
// Consecutive blocks on an XCD = the 8 m-tiles of one n-tile (B L2-reuse);
// A (shb, 256KB total) is L2-resident so per-block A-staging is cheap.
// 3 barriers total; the 64KB store burst drains at wave retire (no barrier
// behind it), so the CU backfills with the next block immediately.
// LDS 64KB (As+Bs; Cs f32[128][128] overlays both) -> 2 blocks/CU.
// ---------------------------------------------------------------------------
__global__ __launch_bounds__(256)
void gemm_vocab(float* __restrict__ C, const ushort* __restrict__ Ab,
                const ushort* __restrict__ Bswz) {
    __shared__ ushort smem[2 * 128 * 128];         // 64 KB
    ushort* As = smem;
    ushort* Bs = smem + 128 * 128;
    float* Cs = (float*)smem;                      // [128][128] f32 overlay
    const int id = blockIdx.x;
    const int xcd = id & 7, mt = (id >> 3) & 7, g = id >> 6;  // g 0..97
    const int grp = xcd * 98 + g;                  // n-tile 0..783
    if (grp >= 782) return;                        // block-uniform early out
    const int n0 = grp * 128;
    const int m0 = mt * 128;
    const int t = threadIdx.x;
    const int lane = t & 63, wid = t >> 6;
    const int wr = wid >> 1, wc = wid & 1;
    const int l15 = lane & 15, kg = (lane >> 4) * 8;
    const int cr0 = (lane >> 4) * 4;

    // stage A (L2-hit) + B, both linear from pre-swizzled buffers
    const ushort* srca = Ab + (size_t)m0 * 128;
    const ushort* srcb = Bswz + (size_t)n0 * 128;
    #pragma unroll
    for (int f = t; f < 2048; f += 256) {
        *(bf16x8*)&As[f * 8] = *(const bf16x8*)(srca + f * 8);
        *(bf16x8*)&Bs[f * 8] = *(const bf16x8*)(srcb + f * 8);
    }
    __syncthreads();

    f32x4 acc[4][4] = {};
    #pragma unroll
    for (int kc = 0; kc < 4; ++kc) {
        const int cs = kc * 32 + kg;
        bf16x8 af[4], bfr[4];
        #pragma unroll
        for (int i = 0; i < 4; ++i) {
            const int ra = wr * 64 + i * 16 + l15;
            af[i] = *(const bf16x8*)&As[ra * 128 + (cs ^ ((ra & 7) << 3))];
            const int rb = wc * 64 + i * 16 + l15;
            bfr[i] = *(const bf16x8*)&Bs[rb * 128 + (cs ^ ((rb & 7) << 3))];
        }
        #pragma unroll
        for (int i = 0; i < 4; ++i)
            #pragma unroll
            for (int j = 0; j < 4; ++j)
                acc[i][j] = __builtin_amdgcn_mfma_f32_16x16x32_bf16(af[i], bfr[j], acc[i][j], 0, 0, 0);
    }
    __syncthreads();                               // all LDS reads done

    // repack full tile -> Cs[128][128] f32 (2-way bank alias = free)
    #pragma unroll
    for (int j = 0; j < 4; ++j) {
        const int col = wc * 64 + j * 16 + l15;
        #pragma unroll
        for (int i = 0; i < 4; ++i) {
            const int row = wr * 64 + i * 16 + cr0;
            #pragma unroll
            for (int q = 0; q < 4; ++q)
                Cs[(row + q) * 128 + col] = acc[i][j][q];
        }
    }
    __syncthreads();

    // store 64 KB coalesced; kernel retires while stores drain
    #pragma unroll
    for (int f = t; f < 4096; f += 256) {
        const int r = f >> 5, c4 = (f & 31) * 4;
        if (n0 + c4 < NVOCAB) {
            const f32x4 v = *(const f32x4*)&Cs[r * 128 + c4];
            *(f32x4*)(C + (size_t)(m0 + r) * NVOCAB + n0 + c4) = v;
        }
    }
}

extern "C" void kernel_launch(void* const* d_in, const int* in_sizes, int n_in,
                              void* d_out, int out_size, void* d_ws, size_t ws_size,
                              hipStream_t stream) {
    const int*   x   = (const int*)d_in[0];
    const int*   ei  = (const int*)d_in[1];
    const float* emb = (const float*)d_in[3];
    const float* Wg  = (const float*)d_in[4];
    const float* Wih = (const float*)d_in[5];
    const float* Whh = (const float*)d_in[6];
    const float* bih = (const float*)d_in[7];
    const float* bhh = (const float*)d_in[8];
    const float* W1  = (const float*)d_in[9];
    const float* b1  = (const float*)d_in[10];
    const float* W2  = (const float*)d_in[11];
    const float* b2  = (const float*)d_in[12];
    const float* qw  = (const float*)d_in[13];
    const float* qb  = (const float*)d_in[14];
    const float* W3  = (const float*)d_in[15];
    const float* b3  = (const float*)d_in[16];
    float* out = (float*)d_out;

    // workspace layout (float offsets); ~66 MB
    float*  ws     = (float*)d_ws;
    ushort* hb     = (ushort*)ws;                  // 6,553,600 bf16 (3,276,800 f)
    ushort* aggb   = (ushort*)(ws + 3276800);      // 6,553,600 bf16 (pre-swizzled)
    ushort* Wc     = (ushort*)(ws + 6553600);      // 49,152 bf16 (24,576 f)
    ushort* Whhb   = (ushort*)(ws + 6578176);      // 49,152 bf16 (24,576 f)
    ushort* W2b    = (ushort*)(ws + 6602752);      // 16,384 bf16 (8,192 f)
    ushort* shb    = (ushort*)(ws + 6610944);      // 131,072 bf16 (65,536 f)
    ushort* embswz = (ushort*)(ws + 6676480);      // 12,812,288 bf16 (6,406,144 f)
    int*    cnt    = (int*)(ws + 13082624);        // 51,200
    int*    esrc   = cnt + NNODES;                 // 3,276,800

    hipMemsetAsync(cnt, 0, NNODES * sizeof(int), stream);

    // gather + slot-CSR fill + emb pre-swizzle + Wcomb + Whh/W2 pre-cvt
    prep_kernel<<<11280, 256, 0, stream>>>(x, emb, hb, ei, cnt, esrc, embswz,
                                           Wih, Wg, Wc, Whh, Whhb, W2, W2b);

    // gather-sum S = sum hb[src] (deep TLP; writes pre-swizzled aggb)
    agg_kernel<<<12800, 256, 0, stream>>>(cnt, esrc, hb, aggb);

    // fused GRU (gi/gh in registers; h bf16 in place)
    gru_fused<<<400, 512, 0, stream>>>(aggb, Wc, Whhb, bih, bhh, hb);

    // fused t2 + attention + sh -> shb (bf16, pre-swizzled)
    attn_sh<<<512, 256, 0, stream>>>(hb, W1, b1, W2b, qw, qb, b2, W3, b3, shb);

    // out = s_h @ emb^T (v4: 1 tile/block, retire-drained stores)
    gemm_vocab<<<6272, 256, 0, stream>>>(out, shb, embswz);
}